// Round 1
// baseline (110.074 us; speedup 1.0000x reference)
//
#include <hip/hip_runtime.h>

#pragma clang fp contract(off)

namespace {

constexpr int HD    = 96;           // H = W = D = 96
constexpr int STRX  = HD * HD;      // stride along x (H axis)
constexpr int VOL   = HD * HD * HD; // 884736 per batch
constexpr int NSTEPS = 50;
constexpr int DIMI  = HD - 1;       // 95
constexpr float DIMF = 95.0f;
constexpr float MAXC = 100.0f;

struct V3 { float x, y, z; };

__device__ __forceinline__ int clampi(int v) {
    return v < 0 ? 0 : (v > DIMI ? DIMI : v);
}

// Issue the 6 neighbor loads for the central-difference gradient at the
// voxel that position p maps to (idx = clip(trunc(p*95), 0, 95), edge-padded).
__device__ __forceinline__ void load_nb(const float* __restrict__ base,
                                        const V3 p, float nb[6]) {
    int x = clampi((int)(p.x * DIMF));
    int y = clampi((int)(p.y * DIMF));
    int z = clampi((int)(p.z * DIMF));
    int xp = x < DIMI ? x + 1 : DIMI, xm = x > 0 ? x - 1 : 0;
    int yp = y < DIMI ? y + 1 : DIMI, ym = y > 0 ? y - 1 : 0;
    int zp = z < DIMI ? z + 1 : DIMI, zm = z > 0 ? z - 1 : 0;
    int rowx = x * STRX;
    nb[0] = base[xp * STRX + y * HD + z];
    nb[1] = base[xm * STRX + y * HD + z];
    nb[2] = base[rowx + yp * HD + z];
    nb[3] = base[rowx + ym * HD + z];
    nb[4] = base[rowx + y * HD + zp];
    nb[5] = base[rowx + y * HD + zm];
}

// a_i = -(2 v_i (g.v) - g_i |v|^2), clipped to +-100  (einsum collapsed)
__device__ __forceinline__ V3 accel_from(const float nb[6], const V3 v) {
    float gx = (nb[0] - nb[1]) * 0.5f;
    float gy = (nb[2] - nb[3]) * 0.5f;
    float gz = (nb[4] - nb[5]) * 0.5f;
    float gv = gx * v.x + gy * v.y + gz * v.z;
    float vv = v.x * v.x + v.y * v.y + v.z * v.z;
    V3 a;
    a.x = -(2.0f * v.x * gv - gx * vv);
    a.y = -(2.0f * v.y * gv - gy * vv);
    a.z = -(2.0f * v.z * gv - gz * vv);
    a.x = fminf(fmaxf(a.x, -MAXC), MAXC);
    a.y = fminf(fmaxf(a.y, -MAXC), MAXC);
    a.z = fminf(fmaxf(a.z, -MAXC), MAXC);
    return a;
}

__device__ __forceinline__ V3 axpy(const V3 a, float s, const V3 b) {
    // a + s*b
    V3 r; r.x = a.x + s * b.x; r.y = a.y + s * b.y; r.z = a.z + s * b.z;
    return r;
}

} // namespace

__global__ void __launch_bounds__(256)
geodesic_kernel(const float* __restrict__ sp, const float* __restrict__ sv,
                const float* __restrict__ Phi, float* __restrict__ out,
                int B) {
    if (blockIdx.x > 0) {
        // ---- warming blocks: stream Phi once into L2/L3 ----
        int nblk = gridDim.x - 1;
        const float4* p4 = (const float4*)Phi;
        long total4 = (long)B * VOL / 4;
        float acc = 0.f;
        for (long i = (long)(blockIdx.x - 1) * blockDim.x + threadIdx.x;
             i < total4; i += (long)nblk * blockDim.x) {
            float4 v = p4[i];
            acc += v.x + v.y + v.z + v.w;
        }
        asm volatile("" :: "v"(acc)); // keep loads live (no DCE)
        return;
    }

    int b = threadIdx.x;
    if (b >= B) return;

    const float H   = 0.1f;
    const float H05 = 0.5f * H;              // == float(0.05)
    const float H6  = (float)(0.1 / 6.0);    // h/6 as the reference computes it

    const float* __restrict__ base = Phi + (long)b * VOL;
    float* __restrict__ opos = out;                           // (B,50,3)
    float* __restrict__ ovel = out + (long)B * NSTEPS * 3;    // (B,50,3)

    V3 pos = { sp[b * 3 + 0], sp[b * 3 + 1], sp[b * 3 + 2] };
    V3 vel = { sv[b * 3 + 0], sv[b * 3 + 1], sv[b * 3 + 2] };

    // t = 0 output
    long o0 = (long)b * NSTEPS * 3;
    opos[o0 + 0] = pos.x; opos[o0 + 1] = pos.y; opos[o0 + 2] = pos.z;
    ovel[o0 + 0] = vel.x; ovel[o0 + 1] = vel.y; ovel[o0 + 2] = vel.z;

    for (int t = 1; t < NSTEPS; ++t) {
        // ---- round A: sample positions p1, p2 known up-front ----
        V3 p1 = pos;
        V3 p2 = axpy(pos, H05, vel);          // pos + 0.5h*k1v
        float nb1[6], nb2[6];
        load_nb(base, p1, nb1);               // 12 independent loads issued
        load_nb(base, p2, nb2);               // together: 1 memory round-trip

        V3 k1a = accel_from(nb1, vel);
        V3 k2v = axpy(vel, H05, k1a);
        V3 k2a = accel_from(nb2, k2v);
        V3 k3v = axpy(vel, H05, k2a);

        // ---- round B: p3 needs only k1a, p4 needs only k2a ----
        V3 p3 = axpy(pos, H05, k2v);          // pos + 0.5h*k2v
        V3 p4 = axpy(pos, H, k3v);            // pos + h*k3v
        float nb3[6], nb4[6];
        load_nb(base, p3, nb3);
        load_nb(base, p4, nb4);

        V3 k3a = accel_from(nb3, k3v);
        V3 k4v = axpy(vel, H, k3a);
        V3 k4a = accel_from(nb4, k4v);

        // pos += h/6 (k1v + 2 k2v + 2 k3v + k4v);  k1v = vel
        V3 sv_;
        sv_.x = vel.x + 2.0f * k2v.x + 2.0f * k3v.x + k4v.x;
        sv_.y = vel.y + 2.0f * k2v.y + 2.0f * k3v.y + k4v.y;
        sv_.z = vel.z + 2.0f * k2v.z + 2.0f * k3v.z + k4v.z;
        V3 sa;
        sa.x = k1a.x + 2.0f * k2a.x + 2.0f * k3a.x + k4a.x;
        sa.y = k1a.y + 2.0f * k2a.y + 2.0f * k3a.y + k4a.y;
        sa.z = k1a.z + 2.0f * k2a.z + 2.0f * k3a.z + k4a.z;
        pos = axpy(pos, H6, sv_);
        vel = axpy(vel, H6, sa);

        long ot = (long)b * NSTEPS * 3 + (long)t * 3;
        opos[ot + 0] = pos.x; opos[ot + 1] = pos.y; opos[ot + 2] = pos.z;
        ovel[ot + 0] = vel.x; ovel[ot + 1] = vel.y; ovel[ot + 2] = vel.z;
    }
}

extern "C" void kernel_launch(void* const* d_in, const int* in_sizes, int n_in,
                              void* d_out, int out_size, void* d_ws, size_t ws_size,
                              hipStream_t stream) {
    const float* sp  = (const float*)d_in[0];
    const float* sv  = (const float*)d_in[1];
    const float* phi = (const float*)d_in[2];
    float* out = (float*)d_out;
    int B = in_sizes[0] / 3;   // = 2

    // block 0 integrates (threads 0..B-1); 128 blocks warm Phi into cache
    geodesic_kernel<<<dim3(1 + 128), dim3(256), 0, stream>>>(sp, sv, phi, out, B);
}